// Round 1
// baseline (103.102 us; speedup 1.0000x reference)
//
#include <hip/hip_runtime.h>

#define NPARTS 16
#define NIN 4
#define NH 16
#define NO 3
#define NEG_SLOPE 0.01f
#define BN_EPS 1e-5f
#define NN 64
#define NF 512

// One block per (batch, part) pair; 512 threads = one per feature column fi.
// All global loads/stores are contiguous 2KB runs per row -> fully coalesced.
// Per-part weights staged in LDS (wave-uniform reads -> broadcast, no bank
// conflicts). BN folded into W2/shift: y = (h.W2 + b2 - mean)*sc + beta
//   = h.(W2*sc) + ((b2 - mean)*sc + beta).
__global__ __launch_bounds__(512)
void agg_joint_kernel(const float* __restrict__ x,
                      const int* __restrict__ parts,
                      const float* __restrict__ W1,
                      const float* __restrict__ b1,
                      const float* __restrict__ W2,
                      const float* __restrict__ b2,
                      const float* __restrict__ gamma,
                      const float* __restrict__ beta,
                      const float* __restrict__ mean,
                      const float* __restrict__ var,
                      float* __restrict__ out)
{
    const int p  = blockIdx.x & (NPARTS - 1);
    const int bi = blockIdx.x >> 4;
    const int fi = threadIdx.x;

    __shared__ float s_w1[NIN * NH];   // [j][h]
    __shared__ float s_b1[NH];
    __shared__ float s_w2[NH * NO];    // [h][o], pre-scaled by BN scale
    __shared__ float s_shift[NO];      // (b2 - mean)*sc + beta
    __shared__ int   s_nidx[NIN];

    const int t = threadIdx.x;
    if (t < NIN * NH) s_w1[t] = W1[p * NIN * NH + t];
    if (t < NH)       s_b1[t] = b1[p * NH + t];
    if (t < NH * NO) {
        const int o = t % NO;
        const float sc = gamma[p * NO + o] * rsqrtf(var[p * NO + o] + BN_EPS);
        s_w2[t] = W2[p * NH * NO + t] * sc;
    }
    if (t < NO) {
        const float sc = gamma[p * NO + t] * rsqrtf(var[p * NO + t] + BN_EPS);
        s_shift[t] = (b2[p * NO + t] - mean[p * NO + t]) * sc + beta[p * NO + t];
    }
    if (t < NIN) s_nidx[t] = parts[p * NIN + t];
    __syncthreads();

    // Gather the 4 x values for this (bi, fi) and part p.
    const float* xb = x + (size_t)bi * NN * NF + fi;
    float xv[NIN];
#pragma unroll
    for (int j = 0; j < NIN; ++j) xv[j] = xb[(size_t)s_nidx[j] * NF];

    // Hidden layer: 4 -> 16, leaky ReLU.
    float hh[NH];
#pragma unroll
    for (int k = 0; k < NH; ++k) {
        float a = s_b1[k];
#pragma unroll
        for (int j = 0; j < NIN; ++j) a = fmaf(xv[j], s_w1[j * NH + k], a);
        hh[k] = a > 0.0f ? a : NEG_SLOPE * a;
    }

    // Output layer: 16 -> 3 with folded BN, leaky ReLU, coalesced store.
    float* ob = out + ((size_t)bi * (NPARTS * NO) + p * NO) * NF + fi;
#pragma unroll
    for (int o = 0; o < NO; ++o) {
        float a = s_shift[o];
#pragma unroll
        for (int k = 0; k < NH; ++k) a = fmaf(hh[k], s_w2[k * NO + o], a);
        a = a > 0.0f ? a : NEG_SLOPE * a;
        ob[(size_t)o * NF] = a;
    }
}

extern "C" void kernel_launch(void* const* d_in, const int* in_sizes, int n_in,
                              void* d_out, int out_size, void* d_ws, size_t ws_size,
                              hipStream_t stream) {
    const float* x     = (const float*)d_in[0];
    const int*   parts = (const int*)d_in[1];
    const float* W1    = (const float*)d_in[2];
    const float* b1    = (const float*)d_in[3];
    const float* W2    = (const float*)d_in[4];
    const float* b2    = (const float*)d_in[5];
    const float* gamma = (const float*)d_in[6];
    const float* beta  = (const float*)d_in[7];
    const float* mean  = (const float*)d_in[8];
    const float* var   = (const float*)d_in[9];
    float* out = (float*)d_out;

    const int batch = in_sizes[0] / (NN * NF);   // 256
    dim3 grid(batch * NPARTS);
    dim3 block(NF);
    agg_joint_kernel<<<grid, block, 0, stream>>>(
        x, parts, W1, b1, W2, b2, gamma, beta, mean, var, out);
}

// Round 2
// 100.295 us; speedup vs baseline: 1.0280x; 1.0280x over previous
//
#include <hip/hip_runtime.h>

#define NPARTS 16
#define NIN 4
#define NH 16
#define NO 3
#define NEG_SLOPE 0.01f
#define BN_EPS 1e-5f
#define NN 64
#define NF 512
#define NF4 (NF / 4)   // 128 float4 groups per row

// Branchless leaky ReLU: a>=0 -> a ; a<0 -> a + (slope-1)*a = slope*a
__device__ __forceinline__ float leaky1(float a) {
    return fmaf(fminf(a, 0.0f), NEG_SLOPE - 1.0f, a);
}
__device__ __forceinline__ float4 leaky4(float4 a) {
    a.x = leaky1(a.x); a.y = leaky1(a.y); a.z = leaky1(a.z); a.w = leaky1(a.w);
    return a;
}
// d = v * s + d  (vector * broadcast-scalar accumulate)
__device__ __forceinline__ float4 fma4s(float4 v, float s, float4 d) {
    d.x = fmaf(v.x, s, d.x); d.y = fmaf(v.y, s, d.y);
    d.z = fmaf(v.z, s, d.z); d.w = fmaf(v.w, s, d.w);
    return d;
}
__device__ __forceinline__ float4 splat4(float s) {
    float4 r; r.x = s; r.y = s; r.z = s; r.w = s; return r;
}

// One block per (batch bi, part p); 128 threads = one float4 group of fi each.
// All global loads/stores are 16 B/lane fully-coalesced float4.
// Weights for part p staged in LDS (all reads wave-uniform -> broadcast).
// BN folded: y = h.(W2*sc) + ((b2-mean)*sc + beta), sc = gamma*rsqrt(var+eps).
__global__ __launch_bounds__(128)
void agg_joint_kernel(const float* __restrict__ x,
                      const int* __restrict__ parts,
                      const float* __restrict__ W1,
                      const float* __restrict__ b1,
                      const float* __restrict__ W2,
                      const float* __restrict__ b2,
                      const float* __restrict__ gamma,
                      const float* __restrict__ beta,
                      const float* __restrict__ mean,
                      const float* __restrict__ var,
                      float* __restrict__ out)
{
    const int p  = blockIdx.x & (NPARTS - 1);
    const int bi = blockIdx.x >> 4;
    const int t  = threadIdx.x;   // fi4 group index, 0..127

    __shared__ float s_w1[NIN * NH];   // [j][h]
    __shared__ float s_b1[NH];
    __shared__ float s_w2[NH * NO];    // [h][o], pre-scaled by BN scale
    __shared__ float s_shift[NO];      // (b2 - mean)*sc + beta
    __shared__ int   s_nidx[NIN];

    if (t < NIN * NH) s_w1[t] = W1[p * NIN * NH + t];
    if (t < NH)       s_b1[t] = b1[p * NH + t];
    if (t < NH * NO) {
        const int o = t % NO;
        const float sc = gamma[p * NO + o] * rsqrtf(var[p * NO + o] + BN_EPS);
        s_w2[t] = W2[p * NH * NO + t] * sc;
    }
    if (t < NO) {
        const float sc = gamma[p * NO + t] * rsqrtf(var[p * NO + t] + BN_EPS);
        s_shift[t] = (b2[p * NO + t] - mean[p * NO + t]) * sc + beta[p * NO + t];
    }
    if (t < NIN) s_nidx[t] = parts[p * NIN + t];
    __syncthreads();

    // Gather 4 x rows' float4 for this (bi, fi4): 16 B/lane, coalesced.
    float4 xv[NIN];
#pragma unroll
    for (int j = 0; j < NIN; ++j) {
        const float4* xr =
            (const float4*)(x + ((size_t)bi * NN + s_nidx[j]) * NF);
        xv[j] = xr[t];
    }

    // Output accumulators initialized with the folded BN shift.
    float4 acc[NO];
#pragma unroll
    for (int o = 0; o < NO; ++o) acc[o] = splat4(s_shift[o]);

    // Hidden units computed one at a time, accumulated straight into acc.
#pragma unroll
    for (int k = 0; k < NH; ++k) {
        float4 h = splat4(s_b1[k]);
#pragma unroll
        for (int j = 0; j < NIN; ++j) h = fma4s(xv[j], s_w1[j * NH + k], h);
        h = leaky4(h);
#pragma unroll
        for (int o = 0; o < NO; ++o) acc[o] = fma4s(h, s_w2[k * NO + o], acc[o]);
    }

    // Final leaky ReLU + coalesced float4 stores.
    float4* ob = (float4*)(out + ((size_t)bi * (NPARTS * NO) + p * NO) * NF);
#pragma unroll
    for (int o = 0; o < NO; ++o) ob[(size_t)o * NF4 + t] = leaky4(acc[o]);
}

extern "C" void kernel_launch(void* const* d_in, const int* in_sizes, int n_in,
                              void* d_out, int out_size, void* d_ws, size_t ws_size,
                              hipStream_t stream) {
    const float* x     = (const float*)d_in[0];
    const int*   parts = (const int*)d_in[1];
    const float* W1    = (const float*)d_in[2];
    const float* b1    = (const float*)d_in[3];
    const float* W2    = (const float*)d_in[4];
    const float* b2    = (const float*)d_in[5];
    const float* gamma = (const float*)d_in[6];
    const float* beta  = (const float*)d_in[7];
    const float* mean  = (const float*)d_in[8];
    const float* var   = (const float*)d_in[9];
    float* out = (float*)d_out;

    const int batch = in_sizes[0] / (NN * NF);   // 256
    dim3 grid(batch * NPARTS);
    dim3 block(128);
    agg_joint_kernel<<<grid, block, 0, stream>>>(
        x, parts, W1, b1, W2, b2, gamma, beta, mean, var, out);
}